// Round 1
// baseline (1667.140 us; speedup 1.0000x reference)
//
#include <hip/hip_runtime.h>
#include <hip/hip_bf16.h>

// Problem constants
#define HID   4096
#define OUTF  4096
#define NTOK  8192          // B*S = 4*2048
#define PROJ_STRIDE 33554432ull  // NTOK*OUTF

typedef _Float16 f16x8 __attribute__((ext_vector_type(8)));
typedef _Float16 f16x4 __attribute__((ext_vector_type(4)));
typedef float    f32x4 __attribute__((ext_vector_type(4)));

// ---------------------------------------------------------------------------
// Kernel W: int32 weights (values -8..7) -> _Float16, 4 elems/thread
// ---------------------------------------------------------------------------
__global__ __launch_bounds__(256) void cvt_weights(const int* __restrict__ w,
                                                   _Float16* __restrict__ o,
                                                   int n4) {
    int i = blockIdx.x * blockDim.x + threadIdx.x;
    if (i < n4) {
        int4 v = ((const int4*)w)[i];
        f16x4 h;
        h.x = (_Float16)(float)v.x;
        h.y = (_Float16)(float)v.y;
        h.z = (_Float16)(float)v.z;
        h.w = (_Float16)(float)v.w;
        ((f16x4*)o)[i] = h;
    }
}

// ---------------------------------------------------------------------------
// Kernel A: per-token transform + quantize.
//   X = hs[t] as 64x64 (row l, col r)
//   T1 = left @ X ; XT = T1 @ right
//   a_scale = max(maxabs(XT)/7, 1e-8)
//   xq = clip(rint(XT / a_scale), -8, 7)  -> stored as f16 (exact)
// One 256-thread block per token. Wave w handles m in [w*16, w*16+16),
// lane handles column r/n = lane. LDS broadcasts are wave-uniform (free);
// X/T1 column reads are lane-consecutive (conflict-free).
// ---------------------------------------------------------------------------
__global__ __launch_bounds__(256) void transform_quant(
    const float* __restrict__ hs, const float* __restrict__ left,
    const float* __restrict__ right, _Float16* __restrict__ xq,
    float* __restrict__ ascale) {
    __shared__ float Xs[64 * 64];   // reused for T1 in stage 2
    __shared__ float Ls[64 * 64];
    __shared__ float Rs[64 * 64];
    __shared__ float red[256];

    const int t   = blockIdx.x;
    const int tid = threadIdx.x;
    const int n   = tid & 63;    // column (r in stage 1, n in stage 2)
    const int ms  = tid >> 6;    // wave id -> m block [ms*16, ms*16+16)

    // Stage inputs to LDS (coalesced float4)
    {
        const float4* src = (const float4*)(hs + (size_t)t * HID);
        const float4* ls  = (const float4*)left;
        const float4* rs  = (const float4*)right;
        float4* xd = (float4*)Xs;
        float4* ld = (float4*)Ls;
        float4* rd = (float4*)Rs;
        #pragma unroll
        for (int i = tid; i < 1024; i += 256) {
            xd[i] = src[i];
            ld[i] = ls[i];
            rd[i] = rs[i];
        }
    }
    __syncthreads();

    float acc[16];

    // Stage 1: T1[m][r] = sum_l left[m][l] * X[l][r]
    #pragma unroll
    for (int mm = 0; mm < 16; mm++) acc[mm] = 0.f;
    for (int l = 0; l < 64; l++) {
        float x = Xs[l * 64 + n];
        #pragma unroll
        for (int mm = 0; mm < 16; mm++)
            acc[mm] = fmaf(Ls[(ms * 16 + mm) * 64 + l], x, acc[mm]);
    }
    __syncthreads();                 // all X reads done; reuse Xs as T1
    #pragma unroll
    for (int mm = 0; mm < 16; mm++) Xs[(ms * 16 + mm) * 64 + n] = acc[mm];
    __syncthreads();

    // Stage 2: XT[m][n] = sum_r T1[m][r] * right[r][n]
    #pragma unroll
    for (int mm = 0; mm < 16; mm++) acc[mm] = 0.f;
    for (int r = 0; r < 64; r++) {
        float rv = Rs[r * 64 + n];
        #pragma unroll
        for (int mm = 0; mm < 16; mm++)
            acc[mm] = fmaf(Xs[(ms * 16 + mm) * 64 + r], rv, acc[mm]);
    }

    // maxabs reduction over the block
    float mx = 0.f;
    #pragma unroll
    for (int mm = 0; mm < 16; mm++) mx = fmaxf(mx, fabsf(acc[mm]));
    red[tid] = mx;
    __syncthreads();
    for (int s = 128; s > 0; s >>= 1) {
        if (tid < s) red[tid] = fmaxf(red[tid], red[tid + s]);
        __syncthreads();
    }
    float scale = fmaxf(red[0] * (1.0f / 7.0f), 1e-8f);

    // Quantize (true division + rint to match numpy round-half-even)
    #pragma unroll
    for (int mm = 0; mm < 16; mm++) {
        float q = rintf(acc[mm] / scale);
        q = fminf(fmaxf(q, -8.f), 7.f);
        xq[(size_t)t * HID + (ms * 16 + mm) * 64 + n] = (_Float16)q;
    }
    if (tid == 0) ascale[t] = scale;
}

// ---------------------------------------------------------------------------
// Kernel G: m97-style f16 MFMA GEMM, 128x128 tile, BK=32, 256 thr (4 waves 2x2),
// global_load_lds width-16 staging, fused scaling epilogue.
//   out[proj][t][o] = (sum_k xq[t][k] * w[proj][o][k]) * ascale[t] * wscale[o]
// ---------------------------------------------------------------------------
#define BM 128
#define BN 128
#define BK 32

__global__ __launch_bounds__(256) void gemm_qkv(
    const _Float16* __restrict__ xq, const float* __restrict__ ascale,
    const _Float16* __restrict__ wh, const float* __restrict__ sq,
    const float* __restrict__ sk, const float* __restrict__ sv,
    float* __restrict__ out) {
    __shared__ _Float16 As[BM * BK];  // 8 KB, row-major [row][BK]
    __shared__ _Float16 Bs[BN * BK];  // 8 KB

    const int tid  = threadIdx.x;
    const int lane = tid & 63;
    const int wave = tid >> 6;
    const int wr   = wave >> 1;      // 2x2 wave grid, each wave does 64x64
    const int wc   = wave & 1;
    const int ml   = lane & 15;
    const int kq   = lane >> 4;

    const int mb   = blockIdx.x;          // 64 M-tiles
    const int proj = blockIdx.y >> 5;     // 0..2
    const int nb   = blockIdx.y & 31;     // 32 N-tiles

    const _Float16* wp = wh + (size_t)proj * ((size_t)OUTF * HID);
    const float* wscale = (proj == 0) ? sq : ((proj == 1) ? sk : sv);

    const size_t rowA0 = (size_t)mb * BM;
    const size_t rowB0 = (size_t)nb * BN;

    f32x4 acc[4][4];
    #pragma unroll
    for (int i = 0; i < 4; i++)
        #pragma unroll
        for (int j = 0; j < 4; j++) {
            f32x4 z = {0.f, 0.f, 0.f, 0.f};
            acc[i][j] = z;
        }

    for (int k0 = 0; k0 < HID; k0 += BK) {
        // Stage A tile: 128x32 f16 = 8 KB = 512 16B-chunks; chunk c -> row c/4, kchunk c%4
        #pragma unroll
        for (int tch = 0; tch < 2; tch++) {
            int c   = tid + tch * 256;
            int row = c >> 2, kc = c & 3;
            const _Float16* g = xq + (rowA0 + row) * HID + k0 + kc * 8;
            __builtin_amdgcn_global_load_lds(
                (const __attribute__((address_space(1))) void*)g,
                (__attribute__((address_space(3))) void*)(As + c * 8), 16, 0, 0);
        }
        #pragma unroll
        for (int tch = 0; tch < 2; tch++) {
            int c   = tid + tch * 256;
            int row = c >> 2, kc = c & 3;
            const _Float16* g = wp + (rowB0 + row) * HID + k0 + kc * 8;
            __builtin_amdgcn_global_load_lds(
                (const __attribute__((address_space(1))) void*)g,
                (__attribute__((address_space(3))) void*)(Bs + c * 8), 16, 0, 0);
        }
        __syncthreads();

        f16x8 af[4], bfr[4];
        #pragma unroll
        for (int i = 0; i < 4; i++)
            af[i] = *(const f16x8*)(As + (wr * 64 + i * 16 + ml) * BK + kq * 8);
        #pragma unroll
        for (int j = 0; j < 4; j++)
            bfr[j] = *(const f16x8*)(Bs + (wc * 64 + j * 16 + ml) * BK + kq * 8);

        #pragma unroll
        for (int i = 0; i < 4; i++)
            #pragma unroll
            for (int j = 0; j < 4; j++)
                acc[i][j] = __builtin_amdgcn_mfma_f32_16x16x32_f16(
                    af[i], bfr[j], acc[i][j], 0, 0, 0);
        __syncthreads();
    }

    // Epilogue: C/D layout col=lane&15, row=(lane>>4)*4+reg (verified m89/m91)
    #pragma unroll
    for (int i = 0; i < 4; i++) {
        #pragma unroll
        for (int rg = 0; rg < 4; rg++) {
            int row  = mb * BM + wr * 64 + i * 16 + kq * 4 + rg;
            float as = ascale[row];
            #pragma unroll
            for (int j = 0; j < 4; j++) {
                int col = nb * BN + wc * 64 + j * 16 + ml;
                out[(size_t)proj * PROJ_STRIDE + (size_t)row * OUTF + col] =
                    acc[i][j][rg] * as * wscale[col];
            }
        }
    }
}

// ---------------------------------------------------------------------------
// Launch
// ---------------------------------------------------------------------------
extern "C" void kernel_launch(void* const* d_in, const int* in_sizes, int n_in,
                              void* d_out, int out_size, void* d_ws, size_t ws_size,
                              hipStream_t stream) {
    const float* hs    = (const float*)d_in[0];
    const float* left  = (const float*)d_in[1];
    const float* right = (const float*)d_in[2];
    const int*   wq    = (const int*)d_in[3];
    const float* sq    = (const float*)d_in[4];
    const int*   wk    = (const int*)d_in[5];
    const float* sk    = (const float*)d_in[6];
    const int*   wv    = (const int*)d_in[7];
    const float* sv    = (const float*)d_in[8];
    float* out = (float*)d_out;

    // Workspace layout
    //   xqh    : NTOK*HID f16          = 67,108,864 B
    //   ascale : NTOK f32              =     32,768 B
    //   wh     : 3*OUTF*HID f16        = 100,663,296 B
    _Float16* xqh   = (_Float16*)d_ws;
    float*    ascl  = (float*)((char*)d_ws + 67108864ull);
    _Float16* wh    = (_Float16*)((char*)d_ws + 67141632ull);

    const int nW  = OUTF * HID;       // per-projection weight elements
    const int n4  = nW / 4;
    dim3 cblk(256), cgrd((n4 + 255) / 256);
    cvt_weights<<<cgrd, cblk, 0, stream>>>(wq, wh + 0ull * nW, n4);
    cvt_weights<<<cgrd, cblk, 0, stream>>>(wk, wh + 1ull * (size_t)nW, n4);
    cvt_weights<<<cgrd, cblk, 0, stream>>>(wv, wh + 2ull * (size_t)nW, n4);

    transform_quant<<<dim3(NTOK), dim3(256), 0, stream>>>(hs, left, right, xqh, ascl);

    gemm_qkv<<<dim3(NTOK / BM, 3 * (OUTF / BN)), dim3(256), 0, stream>>>(
        xqh, ascl, wh, sq, sk, sv, out);
}